// Round 6
// baseline (1957.855 us; speedup 1.0000x reference)
//
#include <hip/hip_runtime.h>
#include <stdint.h>

// Problem constants (match reference)
#define USER_N 100000
#define ITEM_N 50000
#define TAG_N  20000
#define NN (USER_N + ITEM_N)   // 150000 interaction-graph nodes
#define MM (ITEM_N + TAG_N)    // 70000 tag-graph nodes
#define DD 64
#define BSH 7                  // bucket = row >> 7 (128 rows/bucket)
#define MAXB 2048              // max buckets (NN>>7 = 1172)

// ---------------------------------------------------------------------------
// JAX threefry2x32 (20 rounds), bit-exact (verified: R1 absmax 0.0).
// ---------------------------------------------------------------------------
__host__ __device__ __forceinline__ void tf2x32(uint32_t k0, uint32_t k1,
                                                uint32_t x0, uint32_t x1,
                                                uint32_t* o0, uint32_t* o1) {
  uint32_t ks2 = k0 ^ k1 ^ 0x1BD11BDAu;
#define ROTL32(v, d) (((v) << (d)) | ((v) >> (32 - (d))))
#define TF_RND(d) { x0 += x1; x1 = ROTL32(x1, d); x1 ^= x0; }
  x0 += k0; x1 += k1;
  TF_RND(13) TF_RND(15) TF_RND(26) TF_RND(6)
  x0 += k1;  x1 += ks2 + 1u;
  TF_RND(17) TF_RND(29) TF_RND(16) TF_RND(24)
  x0 += ks2; x1 += k0 + 2u;
  TF_RND(13) TF_RND(15) TF_RND(26) TF_RND(6)
  x0 += k0;  x1 += k1 + 3u;
  TF_RND(17) TF_RND(29) TF_RND(16) TF_RND(24)
  x0 += k1;  x1 += ks2 + 4u;
  TF_RND(13) TF_RND(15) TF_RND(26) TF_RND(6)
  x0 += ks2; x1 += k0 + 5u;
  *o0 = x0; *o1 = x1;
#undef TF_RND
#undef ROTL32
}

// mask(e; key) * keep-mask, bit-exact vs jax uniform+floor
__device__ __forceinline__ float drop_mask(uint32_t e, uint32_t k0, uint32_t k1) {
  uint32_t o0, o1;
  tf2x32(k0, k1, 0u, e, &o0, &o1);
  uint32_t bits = o0 ^ o1;
  float u = __uint_as_float((bits >> 9) | 0x3F800000u) - 1.0f;
  return floorf(u + 0.9f);
}

// ---------------------------------------------------------------------------
// CSR build, two-pass bucketed (R6): random 16B scatters to a 32MB region
// dirty one 64B line per record (R5: 126MB writeback). Pass A groups edges
// into row-buckets (cursor-sequential writes -> full lines); pass B reads
// bucket-grouped tmp linearly and scatters into an L2-resident ~30KB CSR
// window per bucket. Both passes write mostly-full lines.
// ---------------------------------------------------------------------------

// bucket hist (LDS) + row hist (global), one pass over rows[]
__global__ void bhist_kernel(const int* __restrict__ rows, int* __restrict__ bcnt,
                             int* __restrict__ rcnt, int nE, int nb) {
  __shared__ int h[MAXB];
  for (int t = threadIdx.x; t < MAXB; t += 256) h[t] = 0;
  __syncthreads();
  int e = blockIdx.x * 256 + threadIdx.x;
  if (e < nE) {
    int r = rows[e];
    atomicAdd(&h[r >> BSH], 1);
    atomicAdd(&rcnt[r], 1);
  }
  __syncthreads();
  for (int t = threadIdx.x; t < nb; t += 256) {
    int v = h[t];
    if (v) atomicAdd(&bcnt[t], v);
  }
}

// single-block exclusive scan of bcnt[nb] -> bcur[nb], nb <= 2048
__global__ void bscan_kernel(const int* __restrict__ bcnt, int* __restrict__ bcur, int nb) {
  __shared__ int s[256];
  int t = threadIdx.x;
  int base = t * 8;
  int loc[8];
  int sum = 0;
  for (int k = 0; k < 8; ++k) {
    int v = (base + k < nb) ? bcnt[base + k] : 0;
    loc[k] = sum;
    sum += v;
  }
  s[t] = sum;
  __syncthreads();
  for (int off = 1; off < 256; off <<= 1) {
    int v = (t >= off) ? s[t - off] : 0;
    __syncthreads();
    s[t] += v;
    __syncthreads();
  }
  int excl = s[t] - sum;
  for (int k = 0; k < 8; ++k)
    if (base + k < nb) bcur[base + k] = excl + loc[k];
}

// pass A: edge -> bucket region; record carries {col, v_l0, v_l1, row}.
// Threefry keyed on ORIGINAL edge index e -> bit-exact regardless of order.
__global__ void bucket_scatter_kernel(const int* __restrict__ rows, const int* __restrict__ cols,
                                      const float* __restrict__ vals,
                                      int* __restrict__ bcur, int4* __restrict__ tmp, int nE,
                                      uint32_t ka0, uint32_t ka1, uint32_t kb0, uint32_t kb1) {
  int e = blockIdx.x * 256 + threadIdx.x;
  if (e >= nE) return;
  const float SC = (float)(1.0 / 0.9);
  int r = rows[e];
  float v  = vals[e];
  float v0 = v * drop_mask((uint32_t)e, ka0, ka1) * SC;
  float v1 = v * drop_mask((uint32_t)e, kb0, kb1) * SC;
  int pos = atomicAdd(&bcur[r >> BSH], 1);
  tmp[pos] = make_int4(cols[e], __float_as_int(v0), __float_as_int(v1), r);
}

// pass B: bucket-grouped tmp -> final CSR slot (L2-local window per bucket)
__global__ void finalize_kernel(const int4* __restrict__ tmp, int* __restrict__ cur,
                                int4* __restrict__ rec, int nE) {
  int i = blockIdx.x * 256 + threadIdx.x;
  if (i >= nE) return;
  int4 t = tmp[i];
  int pos = atomicAdd(&cur[t.w], 1);
  rec[pos] = make_int4(t.x, t.y, t.z, 0);
}

// row-pointer scans (R2-verified)
__global__ void scan1_kernel(const int* __restrict__ cnt, int* __restrict__ rp,
                             int* __restrict__ bsum, int n) {
  __shared__ int s[256];
  int t = threadIdx.x;
  int base = blockIdx.x * 1024 + t * 4;
  int c0 = (base + 0 < n) ? cnt[base + 0] : 0;
  int c1 = (base + 1 < n) ? cnt[base + 1] : 0;
  int c2 = (base + 2 < n) ? cnt[base + 2] : 0;
  int c3 = (base + 3 < n) ? cnt[base + 3] : 0;
  int tsum = c0 + c1 + c2 + c3;
  s[t] = tsum;
  __syncthreads();
  for (int off = 1; off < 256; off <<= 1) {
    int v = (t >= off) ? s[t - off] : 0;
    __syncthreads();
    s[t] += v;
    __syncthreads();
  }
  int excl = s[t] - tsum;
  if (base + 0 < n) rp[base + 0] = excl;
  if (base + 1 < n) rp[base + 1] = excl + c0;
  if (base + 2 < n) rp[base + 2] = excl + c0 + c1;
  if (base + 3 < n) rp[base + 3] = excl + c0 + c1 + c2;
  if (t == 255) bsum[blockIdx.x] = s[255];
}

__global__ void scan2_kernel(int* __restrict__ bsum, int B) {
  __shared__ int s[256];
  int t = threadIdx.x;
  int v = (t < B) ? bsum[t] : 0;
  s[t] = v;
  __syncthreads();
  for (int off = 1; off < 256; off <<= 1) {
    int x = (t >= off) ? s[t - off] : 0;
    __syncthreads();
    s[t] += x;
    __syncthreads();
  }
  if (t < B) bsum[t] = s[t] - v;
}

__global__ void scan3_kernel(int* __restrict__ rp, const int* __restrict__ bsum,
                             int* __restrict__ cursor, int n, int nE) {
  int i = blockIdx.x * blockDim.x + threadIdx.x;
  if (i < n) {
    int v = rp[i] + bsum[i >> 10];
    rp[i] = v;
    cursor[i] = v;
  }
  if (i == 0) rp[n] = nE;
}

// ---------------------------------------------------------------------------
// Gather SpMM core, quarter-wave float4 (R6): row = 16 lanes x dwordx4.
// Wave = 4 sub-groups; group `sub` handles edge j+sub each iteration -> 4
// edges per load instruction. WAVE-UNIFORM trip counts (R3 lesson): loop
// bounds depend only on cnt (uniform); shfl idx j+sub < 64 always, and
// edges beyond cnt read v=0-padded meta (exact +0 contribution).
// Cross-group reduce via shfl_xor(16/32).
// ---------------------------------------------------------------------------
template <int VS>
__device__ __forceinline__ float4 gather_row4(int s0, int s1,
                                              const int4* __restrict__ rec,
                                              const float* __restrict__ srcA,
                                              const float* __restrict__ srcB,
                                              int split, int lane, int sub, int fl) {
  float4 a = make_float4(0.f, 0.f, 0.f, 0.f);
  for (int base = s0; base < s1; base += 64) {
    int i = base + lane;
    int4 m = make_int4(0, 0, 0, 0);      // pad: col 0, v 0 (exact +0)
    if (i < s1) m = rec[i];
    int mv = VS ? m.z : m.y;
    int cnt = s1 - base;
    if (cnt > 64) cnt = 64;
    int j = 0;
    for (; j + 8 <= cnt; j += 8) {       // 2 loads in flight
      int   c0 = __shfl(m.x, j + sub);
      float v0 = __uint_as_float((uint32_t)__shfl(mv, j + sub));
      int   c1 = __shfl(m.x, j + 4 + sub);
      float v1 = __uint_as_float((uint32_t)__shfl(mv, j + 4 + sub));
      const float* p0 = (c0 < split) ? (srcA + (size_t)c0 * DD) : (srcB + (size_t)(c0 - split) * DD);
      const float* p1 = (c1 < split) ? (srcA + (size_t)c1 * DD) : (srcB + (size_t)(c1 - split) * DD);
      float4 x0 = ((const float4*)p0)[fl];
      float4 x1 = ((const float4*)p1)[fl];
      a.x += v0 * x0.x; a.y += v0 * x0.y; a.z += v0 * x0.z; a.w += v0 * x0.w;
      a.x += v1 * x1.x; a.y += v1 * x1.y; a.z += v1 * x1.z; a.w += v1 * x1.w;
    }
    for (; j < cnt; j += 4) {
      int   c = __shfl(m.x, j + sub);    // idx <= 60+3 < 64; padded v=0 if >= cnt
      float v = __uint_as_float((uint32_t)__shfl(mv, j + sub));
      const float* p = (c < split) ? (srcA + (size_t)c * DD) : (srcB + (size_t)(c - split) * DD);
      float4 x = ((const float4*)p)[fl];
      a.x += v * x.x; a.y += v * x.y; a.z += v * x.z; a.w += v * x.w;
    }
  }
  a.x += __shfl_xor(a.x, 16); a.y += __shfl_xor(a.y, 16);
  a.z += __shfl_xor(a.z, 16); a.w += __shfl_xor(a.w, 16);
  a.x += __shfl_xor(a.x, 32); a.y += __shfl_xor(a.y, 32);
  a.z += __shfl_xor(a.z, 32); a.w += __shfl_xor(a.w, 32);
  return a;
}

__device__ __forceinline__ float4 lk4(float4 x) {
  x.x = x.x >= 0.0f ? x.x : 0.5f * x.x;
  x.y = x.y >= 0.0f ? x.y : 0.5f * x.y;
  x.z = x.z >= 0.0f ? x.z : 0.5f * x.z;
  x.w = x.w >= 0.0f ? x.w : 0.5f * x.w;
  return x;
}

// Tag-node rows only (rr in [0,TAG_N), graph row = ITEM_N+rr): out = leaky(spmm).
__global__ void gather_tagrows_kernel(const int* __restrict__ rp, const int4* __restrict__ rec,
                                      const float* __restrict__ srcA, const float* __restrict__ srcB,
                                      float* __restrict__ out) {
  int rr = (blockIdx.x * blockDim.x + threadIdx.x) >> 6;
  if (rr >= TAG_N) return;
  int lane = threadIdx.x & 63, sub = lane >> 4, fl = lane & 15;
  int r = rr + ITEM_N;
  float4 a = gather_row4<0>(rp[r], rp[r + 1], rec, srcA, srcB, ITEM_N, lane, sub, fl);
  if (sub == 0) ((float4*)(out + (size_t)rr * DD))[fl] = lk4(a);
}

// Mega gather over NN rows; tag gather for item rows fused inline.
// o = leaky(adj) + (r<USER ? leaky(soc) : leaky(tag_row))
// FINAL=false (layer 0): latOut = o            (no acc RMW)
// FINAL=true  (layer 1): acc += lat[row] + o   (folds layer-0 acc add)
template <int VS, bool FINAL>
__global__ void gather_mega_kernel(
    const int* __restrict__ arp, const int4* __restrict__ arec,
    const int* __restrict__ srp, const int4* __restrict__ srec,
    const int* __restrict__ trp, const int4* __restrict__ trec,
    const float* __restrict__ lat,    // NN x 64: src for adj & soc (& tag item part)
    const float* __restrict__ tagB,   // tag-node src rows (tEmbeds or tg1)
    float* __restrict__ latOut, float* __restrict__ acc) {
  int r = (blockIdx.x * blockDim.x + threadIdx.x) >> 6;
  if (r >= NN) return;
  int lane = threadIdx.x & 63, sub = lane >> 4, fl = lane & 15;
  float4 t = lk4(gather_row4<VS>(arp[r], arp[r + 1], arec, lat, lat, NN, lane, sub, fl));
  float4 b;
  if (r < USER_N) {
    b = lk4(gather_row4<VS>(srp[r], srp[r + 1], srec, lat, lat, NN, lane, sub, fl));
  } else {
    int tr = r - USER_N;
    b = lk4(gather_row4<VS>(trp[tr], trp[tr + 1], trec,
                            lat + (size_t)USER_N * DD, tagB, ITEM_N, lane, sub, fl));
  }
  if (sub == 0) {
    float4 o = make_float4(t.x + b.x, t.y + b.y, t.z + b.z, t.w + b.w);
    if (FINAL) {
      float4 l = ((const float4*)(lat + (size_t)r * DD))[fl];
      float4* ap = (float4*)(acc + (size_t)r * DD) + fl;
      float4 av = *ap;
      av.x += l.x + o.x; av.y += l.y + o.y; av.z += l.z + o.z; av.w += l.w + o.w;
      *ap = av;
    } else {
      ((float4*)(latOut + (size_t)r * DD))[fl] = o;
    }
  }
}

// acc = lat0 = concat(uEmbeds, iEmbeds). acc doubles as the layer-0 gather
// source (layer 0 writes only lat1, so no aliasing hazard).
__global__ void init_kernel(const float4* __restrict__ u, const float4* __restrict__ it,
                            float4* __restrict__ acc) {
  int idx = blockIdx.x * blockDim.x + threadIdx.x;  // over NN*16 float4s
  if (idx >= NN * 16) return;
  const int uN = USER_N * 16;
  acc[idx] = (idx < uN) ? u[idx] : it[idx - uN];
}

extern "C" void kernel_launch(void* const* d_in, const int* in_sizes, int n_in,
                              void* d_out, int out_size, void* d_ws, size_t ws_size,
                              hipStream_t stream) {
  const float* uE    = (const float*)d_in[0];
  const float* iE    = (const float*)d_in[1];
  const float* tEm   = (const float*)d_in[2];
  const int*   adj_r = (const int*)d_in[3];
  const int*   adj_c = (const int*)d_in[4];
  const float* adj_v = (const float*)d_in[5];
  const int*   tag_r = (const int*)d_in[6];
  const int*   tag_c = (const int*)d_in[7];
  const float* tag_v = (const float*)d_in[8];
  const int*   soc_r = (const int*)d_in[9];
  const int*   soc_c = (const int*)d_in[10];
  const float* soc_v = (const float*)d_in[11];
  const int nAdj = in_sizes[5], nTag = in_sizes[8], nSoc = in_sizes[11];

  float* acc = (float*)d_out;

  // Workspace layout (~142 MB; R1's 146.5 MB fit fine)
  int4* a_rec = (int4*)d_ws;                       // nAdj  {col, v_l0, v_l1, 0}
  int4* t_rec = a_rec + nAdj;                      // nTag
  int4* s_rec = t_rec + nTag;                      // nSoc
  int4* tmp   = s_rec + nSoc;                      // nAdj (shared by all 3 builds)
  float* lat1 = (float*)(tmp + nAdj);              // NN*DD
  float* tg1  = lat1 + (size_t)NN * DD;            // TAG_N*DD (tag-node rows only)
  int* ip    = (int*)(tg1 + (size_t)TAG_N * DD);
  int* a_rp  = ip;  ip += NN + 1;
  int* a_cur = ip;  ip += NN;
  int* t_rp  = ip;  ip += MM + 1;
  int* t_cur = ip;  ip += MM;
  int* s_rp  = ip;  ip += USER_N + 1;
  int* s_cur = ip;  ip += USER_N;
  int* bsum  = ip;  ip += 256;
  int* bcnt  = ip;  ip += MAXB;
  int* bcur  = ip;  ip += MAXB;

  // fold_in(key(42), j) for j=0..5 (host-side, deterministic)
  uint32_t kk[6][2];
  for (uint32_t j = 0; j < 6; ++j) tf2x32(0u, 42u, 0u, j, &kk[j][0], &kk[j][1]);

  const int thr = 256;
#define CDIV(a, b) (((a) + (b) - 1) / (b))

  // ---- CSR build (once per call; records carry both layers' values) ----
  struct G { const int* rows; const int* cols; const float* vals; int n; int nE;
             int* rp; int* cur; int4* rec; int k0; int k1; };
  G gs[3] = {
      {adj_r, adj_c, adj_v, NN,     nAdj, a_rp, a_cur, a_rec, 0, 3},
      {tag_r, tag_c, tag_v, MM,     nTag, t_rp, t_cur, t_rec, 1, 4},
      {soc_r, soc_c, soc_v, USER_N, nSoc, s_rp, s_cur, s_rec, 2, 5},
  };
  for (int g = 0; g < 3; ++g) {
    int nb = (gs[g].n + (1 << BSH) - 1) >> BSH;
    hipMemsetAsync(gs[g].cur, 0, (size_t)gs[g].n * sizeof(int), stream);
    hipMemsetAsync(bcnt, 0, (size_t)nb * sizeof(int), stream);
    // bucket hist + row hist in one pass
    bhist_kernel<<<CDIV(gs[g].nE, thr), thr, 0, stream>>>(gs[g].rows, bcnt, gs[g].cur, gs[g].nE, nb);
    bscan_kernel<<<1, 256, 0, stream>>>(bcnt, bcur, nb);
    // pass A: edges -> bucket-grouped tmp (cursor-sequential, full-line writes)
    bucket_scatter_kernel<<<CDIV(gs[g].nE, thr), thr, 0, stream>>>(
        gs[g].rows, gs[g].cols, gs[g].vals, bcur, tmp, gs[g].nE,
        kk[gs[g].k0][0], kk[gs[g].k0][1], kk[gs[g].k1][0], kk[gs[g].k1][1]);
    // row-pointer scan
    int B = CDIV(gs[g].n, 1024);
    scan1_kernel<<<B, 256, 0, stream>>>(gs[g].cur, gs[g].rp, bsum, gs[g].n);
    scan2_kernel<<<1, 256, 0, stream>>>(bsum, B);
    scan3_kernel<<<CDIV(gs[g].n, thr), thr, 0, stream>>>(gs[g].rp, bsum, gs[g].cur, gs[g].n, gs[g].nE);
    // pass B: tmp -> final CSR (per-bucket L2-resident target window)
    finalize_kernel<<<CDIV(gs[g].nE, thr), thr, 0, stream>>>(tmp, gs[g].cur, gs[g].rec, gs[g].nE);
  }

  // ---- init: acc = lat0 = concat(u, i) ----
  init_kernel<<<CDIV(NN * 16, thr), thr, 0, stream>>>(
      (const float4*)uE, (const float4*)iE, (float4*)acc);

  // ---- layer 0 ----
  // tg1 = leaky(tag-spmm) for tag-node rows (layer-1 tag sources)
  gather_tagrows_kernel<<<CDIV(TAG_N * 64, thr), thr, 0, stream>>>(
      t_rp, t_rec, acc + (size_t)USER_N * DD, tEm, tg1);

  // lat1 = combine(leaky(adj), leaky(soc) | leaky(tag item rows)); acc untouched
  gather_mega_kernel<0, false><<<CDIV(NN * 64, thr), thr, 0, stream>>>(
      a_rp, a_rec, s_rp, s_rec, t_rp, t_rec, acc, tEm, lat1, nullptr);

  // ---- layer 1 ----
  // acc += lat1 + combine(leaky(adj), leaky(soc) | leaky(tag item rows))
  gather_mega_kernel<1, true><<<CDIV(NN * 64, thr), thr, 0, stream>>>(
      a_rp, a_rec, s_rp, s_rec, t_rp, t_rec, lat1, tg1, nullptr, acc);
#undef CDIV
}

// Round 7
// 860.081 us; speedup vs baseline: 2.2764x; 2.2764x over previous
//
#include <hip/hip_runtime.h>
#include <stdint.h>

// Problem constants (match reference)
#define USER_N 100000
#define ITEM_N 50000
#define TAG_N  20000
#define NN (USER_N + ITEM_N)   // 150000 interaction-graph nodes
#define MM (ITEM_N + TAG_N)    // 70000 tag-graph nodes
#define DD 64

// ---------------------------------------------------------------------------
// JAX threefry2x32 (20 rounds), bit-exact (verified: R1 absmax 0.0).
// ---------------------------------------------------------------------------
__host__ __device__ __forceinline__ void tf2x32(uint32_t k0, uint32_t k1,
                                                uint32_t x0, uint32_t x1,
                                                uint32_t* o0, uint32_t* o1) {
  uint32_t ks2 = k0 ^ k1 ^ 0x1BD11BDAu;
#define ROTL32(v, d) (((v) << (d)) | ((v) >> (32 - (d))))
#define TF_RND(d) { x0 += x1; x1 = ROTL32(x1, d); x1 ^= x0; }
  x0 += k0; x1 += k1;
  TF_RND(13) TF_RND(15) TF_RND(26) TF_RND(6)
  x0 += k1;  x1 += ks2 + 1u;
  TF_RND(17) TF_RND(29) TF_RND(16) TF_RND(24)
  x0 += ks2; x1 += k0 + 2u;
  TF_RND(13) TF_RND(15) TF_RND(26) TF_RND(6)
  x0 += k0;  x1 += k1 + 3u;
  TF_RND(17) TF_RND(29) TF_RND(16) TF_RND(24)
  x0 += k1;  x1 += ks2 + 4u;
  TF_RND(13) TF_RND(15) TF_RND(26) TF_RND(6)
  x0 += ks2; x1 += k0 + 5u;
  *o0 = x0; *o1 = x1;
#undef TF_RND
#undef ROTL32
}

// keep-mask(e; key), bit-exact vs jax uniform+floor
__device__ __forceinline__ float drop_mask(uint32_t e, uint32_t k0, uint32_t k1) {
  uint32_t o0, o1;
  tf2x32(k0, k1, 0u, e, &o0, &o1);
  uint32_t bits = o0 ^ o1;
  float u = __uint_as_float((bits >> 9) | 0x3F800000u) - 1.0f;
  return floorf(u + 0.9f);
}

// ---------------------------------------------------------------------------
// CSR build (R5-verified): histogram -> hierarchical scan -> fused scatter.
// Direct scatter with per-ROW cursors: ~13 edges/cursor -> low atomic
// contention (R6 lesson: 1172 bucket cursors serialized at 343 GB/s).
// One 16B record per edge {col, val_l0, val_l1, 0}.
// ---------------------------------------------------------------------------
__global__ void hist_kernel(const int* __restrict__ rows, int* __restrict__ cnt, int nE) {
  int e = blockIdx.x * blockDim.x + threadIdx.x;
  if (e < nE) atomicAdd(&cnt[rows[e]], 1);
}

__global__ void scan1_kernel(const int* __restrict__ cnt, int* __restrict__ rp,
                             int* __restrict__ bsum, int n) {
  __shared__ int s[256];
  int t = threadIdx.x;
  int base = blockIdx.x * 1024 + t * 4;
  int c0 = (base + 0 < n) ? cnt[base + 0] : 0;
  int c1 = (base + 1 < n) ? cnt[base + 1] : 0;
  int c2 = (base + 2 < n) ? cnt[base + 2] : 0;
  int c3 = (base + 3 < n) ? cnt[base + 3] : 0;
  int tsum = c0 + c1 + c2 + c3;
  s[t] = tsum;
  __syncthreads();
  for (int off = 1; off < 256; off <<= 1) {
    int v = (t >= off) ? s[t - off] : 0;
    __syncthreads();
    s[t] += v;
    __syncthreads();
  }
  int excl = s[t] - tsum;
  if (base + 0 < n) rp[base + 0] = excl;
  if (base + 1 < n) rp[base + 1] = excl + c0;
  if (base + 2 < n) rp[base + 2] = excl + c0 + c1;
  if (base + 3 < n) rp[base + 3] = excl + c0 + c1 + c2;
  if (t == 255) bsum[blockIdx.x] = s[255];
}

__global__ void scan2_kernel(int* __restrict__ bsum, int B) {
  __shared__ int s[256];
  int t = threadIdx.x;
  int v = (t < B) ? bsum[t] : 0;
  s[t] = v;
  __syncthreads();
  for (int off = 1; off < 256; off <<= 1) {
    int x = (t >= off) ? s[t - off] : 0;
    __syncthreads();
    s[t] += x;
    __syncthreads();
  }
  if (t < B) bsum[t] = s[t] - v;
}

__global__ void scan3_kernel(int* __restrict__ rp, const int* __restrict__ bsum,
                             int* __restrict__ cursor, int n, int nE) {
  int i = blockIdx.x * blockDim.x + threadIdx.x;
  if (i < n) {
    int v = rp[i] + bsum[i >> 10];
    rp[i] = v;
    cursor[i] = v;
  }
  if (i == 0) rp[n] = nE;
}

// Fused scatter: per original edge e, compute BOTH layers' dropped values
// (threefry keyed on e -> bit-exact regardless of CSR position) and store one
// aligned int4 record at the atomically-claimed CSR slot.
__global__ void scatter_fused_kernel(const int* __restrict__ rows, const int* __restrict__ cols,
                                     const float* __restrict__ vals,
                                     int* __restrict__ cursor, int4* __restrict__ rec, int nE,
                                     uint32_t ka0, uint32_t ka1, uint32_t kb0, uint32_t kb1) {
  int e = blockIdx.x * blockDim.x + threadIdx.x;
  if (e >= nE) return;
  const float SC = (float)(1.0 / 0.9);
  float v  = vals[e];
  float v0 = v * drop_mask((uint32_t)e, ka0, ka1) * SC;
  float v1 = v * drop_mask((uint32_t)e, kb0, kb1) * SC;
  int pos = atomicAdd(&cursor[rows[e]], 1);
  rec[pos] = make_int4(cols[e], __float_as_int(v0), __float_as_int(v1), 0);
}

// ---------------------------------------------------------------------------
// Gather SpMM core, quarter-wave float4 (R6-verified): row = 16 lanes x
// dwordx4; wave = 4 sub-groups, group `sub` handles edge j+sub -> 4 edges per
// load instruction, bytes/edge unchanged. WAVE-UNIFORM trip counts (R3
// lesson): loop bounds depend only on uniform cnt; shfl idx j+sub < 64
// always; OOB edges read v=0-padded meta (exact +0). Cross-group reduce via
// shfl_xor(16/32). VS picks the layer's value slot at compile time.
// ---------------------------------------------------------------------------
template <int VS>
__device__ __forceinline__ float4 gather_row4(int s0, int s1,
                                              const int4* __restrict__ rec,
                                              const float* __restrict__ srcA,
                                              const float* __restrict__ srcB,
                                              int split, int lane, int sub, int fl) {
  float4 a = make_float4(0.f, 0.f, 0.f, 0.f);
  for (int base = s0; base < s1; base += 64) {
    int i = base + lane;
    int4 m = make_int4(0, 0, 0, 0);      // pad: col 0, v 0 (exact +0)
    if (i < s1) m = rec[i];
    int mv = VS ? m.z : m.y;
    int cnt = s1 - base;
    if (cnt > 64) cnt = 64;
    int j = 0;
    for (; j + 8 <= cnt; j += 8) {       // 2 loads in flight
      int   c0 = __shfl(m.x, j + sub);
      float v0 = __uint_as_float((uint32_t)__shfl(mv, j + sub));
      int   c1 = __shfl(m.x, j + 4 + sub);
      float v1 = __uint_as_float((uint32_t)__shfl(mv, j + 4 + sub));
      const float* p0 = (c0 < split) ? (srcA + (size_t)c0 * DD) : (srcB + (size_t)(c0 - split) * DD);
      const float* p1 = (c1 < split) ? (srcA + (size_t)c1 * DD) : (srcB + (size_t)(c1 - split) * DD);
      float4 x0 = ((const float4*)p0)[fl];
      float4 x1 = ((const float4*)p1)[fl];
      a.x += v0 * x0.x; a.y += v0 * x0.y; a.z += v0 * x0.z; a.w += v0 * x0.w;
      a.x += v1 * x1.x; a.y += v1 * x1.y; a.z += v1 * x1.z; a.w += v1 * x1.w;
    }
    for (; j < cnt; j += 4) {
      int   c = __shfl(m.x, j + sub);    // idx <= 63; padded v=0 if j+sub >= cnt
      float v = __uint_as_float((uint32_t)__shfl(mv, j + sub));
      const float* p = (c < split) ? (srcA + (size_t)c * DD) : (srcB + (size_t)(c - split) * DD);
      float4 x = ((const float4*)p)[fl];
      a.x += v * x.x; a.y += v * x.y; a.z += v * x.z; a.w += v * x.w;
    }
  }
  a.x += __shfl_xor(a.x, 16); a.y += __shfl_xor(a.y, 16);
  a.z += __shfl_xor(a.z, 16); a.w += __shfl_xor(a.w, 16);
  a.x += __shfl_xor(a.x, 32); a.y += __shfl_xor(a.y, 32);
  a.z += __shfl_xor(a.z, 32); a.w += __shfl_xor(a.w, 32);
  return a;
}

__device__ __forceinline__ float4 lk4(float4 x) {
  x.x = x.x >= 0.0f ? x.x : 0.5f * x.x;
  x.y = x.y >= 0.0f ? x.y : 0.5f * x.y;
  x.z = x.z >= 0.0f ? x.z : 0.5f * x.z;
  x.w = x.w >= 0.0f ? x.w : 0.5f * x.w;
  return x;
}

// Tag-node rows only (rr in [0,TAG_N), graph row = ITEM_N+rr): out = leaky(spmm).
__global__ void gather_tagrows_kernel(const int* __restrict__ rp, const int4* __restrict__ rec,
                                      const float* __restrict__ srcA, const float* __restrict__ srcB,
                                      float* __restrict__ out) {
  int rr = (blockIdx.x * blockDim.x + threadIdx.x) >> 6;
  if (rr >= TAG_N) return;
  int lane = threadIdx.x & 63, sub = lane >> 4, fl = lane & 15;
  int r = rr + ITEM_N;
  float4 a = gather_row4<0>(rp[r], rp[r + 1], rec, srcA, srcB, ITEM_N, lane, sub, fl);
  if (sub == 0) ((float4*)(out + (size_t)rr * DD))[fl] = lk4(a);
}

// Mega gather over NN rows; tag gather for item rows fused inline.
// o = leaky(adj) + (r<USER ? leaky(soc) : leaky(tag_row))
// FINAL=false (layer 0): latOut = o            (no acc RMW)
// FINAL=true  (layer 1): acc += lat[row] + o   (folds layer-0 acc add)
template <int VS, bool FINAL>
__global__ void gather_mega_kernel(
    const int* __restrict__ arp, const int4* __restrict__ arec,
    const int* __restrict__ srp, const int4* __restrict__ srec,
    const int* __restrict__ trp, const int4* __restrict__ trec,
    const float* __restrict__ lat,    // NN x 64: src for adj & soc (& tag item part)
    const float* __restrict__ tagB,   // tag-node src rows (tEmbeds or tg1)
    float* __restrict__ latOut, float* __restrict__ acc) {
  int r = (blockIdx.x * blockDim.x + threadIdx.x) >> 6;
  if (r >= NN) return;
  int lane = threadIdx.x & 63, sub = lane >> 4, fl = lane & 15;
  float4 t = lk4(gather_row4<VS>(arp[r], arp[r + 1], arec, lat, lat, NN, lane, sub, fl));
  float4 b;
  if (r < USER_N) {
    b = lk4(gather_row4<VS>(srp[r], srp[r + 1], srec, lat, lat, NN, lane, sub, fl));
  } else {
    int tr = r - USER_N;
    b = lk4(gather_row4<VS>(trp[tr], trp[tr + 1], trec,
                            lat + (size_t)USER_N * DD, tagB, ITEM_N, lane, sub, fl));
  }
  if (sub == 0) {
    float4 o = make_float4(t.x + b.x, t.y + b.y, t.z + b.z, t.w + b.w);
    if (FINAL) {
      float4 l = ((const float4*)(lat + (size_t)r * DD))[fl];
      float4* ap = (float4*)(acc + (size_t)r * DD) + fl;
      float4 av = *ap;
      av.x += l.x + o.x; av.y += l.y + o.y; av.z += l.z + o.z; av.w += l.w + o.w;
      *ap = av;
    } else {
      ((float4*)(latOut + (size_t)r * DD))[fl] = o;
    }
  }
}

// acc = lat0 = concat(uEmbeds, iEmbeds). acc doubles as the layer-0 gather
// source (layer 0 writes only lat1, so no aliasing hazard).
__global__ void init_kernel(const float4* __restrict__ u, const float4* __restrict__ it,
                            float4* __restrict__ acc) {
  int idx = blockIdx.x * blockDim.x + threadIdx.x;  // over NN*16 float4s
  if (idx >= NN * 16) return;
  const int uN = USER_N * 16;
  acc[idx] = (idx < uN) ? u[idx] : it[idx - uN];
}

extern "C" void kernel_launch(void* const* d_in, const int* in_sizes, int n_in,
                              void* d_out, int out_size, void* d_ws, size_t ws_size,
                              hipStream_t stream) {
  const float* uE    = (const float*)d_in[0];
  const float* iE    = (const float*)d_in[1];
  const float* tEm   = (const float*)d_in[2];
  const int*   adj_r = (const int*)d_in[3];
  const int*   adj_c = (const int*)d_in[4];
  const float* adj_v = (const float*)d_in[5];
  const int*   tag_r = (const int*)d_in[6];
  const int*   tag_c = (const int*)d_in[7];
  const float* tag_v = (const float*)d_in[8];
  const int*   soc_r = (const int*)d_in[9];
  const int*   soc_c = (const int*)d_in[10];
  const float* soc_v = (const float*)d_in[11];
  const int nAdj = in_sizes[5], nTag = in_sizes[8], nSoc = in_sizes[11];

  float* acc = (float*)d_out;

  // Workspace layout (~110 MB; R1's 146.5 MB fit fine)
  int4* a_rec = (int4*)d_ws;                       // nAdj  {col, v_l0, v_l1, 0}
  int4* t_rec = a_rec + nAdj;                      // nTag
  int4* s_rec = t_rec + nTag;                      // nSoc
  float* lat1 = (float*)(s_rec + nSoc);            // NN*DD
  float* tg1  = lat1 + (size_t)NN * DD;            // TAG_N*DD (tag-node rows only)
  int* ip    = (int*)(tg1 + (size_t)TAG_N * DD);
  int* a_rp  = ip;  ip += NN + 1;
  int* a_cur = ip;  ip += NN;
  int* t_rp  = ip;  ip += MM + 1;
  int* t_cur = ip;  ip += MM;
  int* s_rp  = ip;  ip += USER_N + 1;
  int* s_cur = ip;  ip += USER_N;
  int* bsum  = ip;  ip += 256;

  // fold_in(key(42), j) for j=0..5 (host-side, deterministic)
  uint32_t kk[6][2];
  for (uint32_t j = 0; j < 6; ++j) tf2x32(0u, 42u, 0u, j, &kk[j][0], &kk[j][1]);

  const int thr = 256;
#define CDIV(a, b) (((a) + (b) - 1) / (b))

  // ---- CSR build (once per call; records carry both layers' values) ----
  struct G { const int* rows; const int* cols; const float* vals; int n; int nE;
             int* rp; int* cur; int4* rec; int k0; int k1; };
  G gs[3] = {
      {adj_r, adj_c, adj_v, NN,     nAdj, a_rp, a_cur, a_rec, 0, 3},
      {tag_r, tag_c, tag_v, MM,     nTag, t_rp, t_cur, t_rec, 1, 4},
      {soc_r, soc_c, soc_v, USER_N, nSoc, s_rp, s_cur, s_rec, 2, 5},
  };
  for (int g = 0; g < 3; ++g) {
    hipMemsetAsync(gs[g].cur, 0, (size_t)gs[g].n * sizeof(int), stream);
    hist_kernel<<<CDIV(gs[g].nE, thr), thr, 0, stream>>>(gs[g].rows, gs[g].cur, gs[g].nE);
    int B = CDIV(gs[g].n, 1024);
    scan1_kernel<<<B, 256, 0, stream>>>(gs[g].cur, gs[g].rp, bsum, gs[g].n);
    scan2_kernel<<<1, 256, 0, stream>>>(bsum, B);
    scan3_kernel<<<CDIV(gs[g].n, thr), thr, 0, stream>>>(gs[g].rp, bsum, gs[g].cur, gs[g].n, gs[g].nE);
    scatter_fused_kernel<<<CDIV(gs[g].nE, thr), thr, 0, stream>>>(
        gs[g].rows, gs[g].cols, gs[g].vals, gs[g].cur, gs[g].rec, gs[g].nE,
        kk[gs[g].k0][0], kk[gs[g].k0][1], kk[gs[g].k1][0], kk[gs[g].k1][1]);
  }

  // ---- init: acc = lat0 = concat(u, i) ----
  init_kernel<<<CDIV(NN * 16, thr), thr, 0, stream>>>(
      (const float4*)uE, (const float4*)iE, (float4*)acc);

  // ---- layer 0 ----
  // tg1 = leaky(tag-spmm) for tag-node rows (layer-1 tag sources)
  gather_tagrows_kernel<<<CDIV(TAG_N * 64, thr), thr, 0, stream>>>(
      t_rp, t_rec, acc + (size_t)USER_N * DD, tEm, tg1);

  // lat1 = combine(leaky(adj), leaky(soc) | leaky(tag item rows)); acc untouched
  gather_mega_kernel<0, false><<<CDIV(NN * 64, thr), thr, 0, stream>>>(
      a_rp, a_rec, s_rp, s_rec, t_rp, t_rec, acc, tEm, lat1, nullptr);

  // ---- layer 1 ----
  // acc += lat1 + combine(leaky(adj), leaky(soc) | leaky(tag item rows))
  gather_mega_kernel<1, true><<<CDIV(NN * 64, thr), thr, 0, stream>>>(
      a_rp, a_rec, s_rp, s_rec, t_rp, t_rec, lat1, tg1, nullptr, acc);
#undef CDIV
}

// Round 8
// 810.686 us; speedup vs baseline: 2.4151x; 1.0609x over previous
//
#include <hip/hip_runtime.h>
#include <stdint.h>

// Problem constants (match reference)
#define USER_N 100000
#define ITEM_N 50000
#define TAG_N  20000
#define NN (USER_N + ITEM_N)   // 150000 interaction-graph nodes
#define MM (ITEM_N + TAG_N)    // 70000 tag-graph nodes
#define DD 64

// ---------------------------------------------------------------------------
// JAX threefry2x32 (20 rounds), bit-exact (verified: R1 absmax 0.0).
// ---------------------------------------------------------------------------
__host__ __device__ __forceinline__ void tf2x32(uint32_t k0, uint32_t k1,
                                                uint32_t x0, uint32_t x1,
                                                uint32_t* o0, uint32_t* o1) {
  uint32_t ks2 = k0 ^ k1 ^ 0x1BD11BDAu;
#define ROTL32(v, d) (((v) << (d)) | ((v) >> (32 - (d))))
#define TF_RND(d) { x0 += x1; x1 = ROTL32(x1, d); x1 ^= x0; }
  x0 += k0; x1 += k1;
  TF_RND(13) TF_RND(15) TF_RND(26) TF_RND(6)
  x0 += k1;  x1 += ks2 + 1u;
  TF_RND(17) TF_RND(29) TF_RND(16) TF_RND(24)
  x0 += ks2; x1 += k0 + 2u;
  TF_RND(13) TF_RND(15) TF_RND(26) TF_RND(6)
  x0 += k0;  x1 += k1 + 3u;
  TF_RND(17) TF_RND(29) TF_RND(16) TF_RND(24)
  x0 += k1;  x1 += ks2 + 4u;
  TF_RND(13) TF_RND(15) TF_RND(26) TF_RND(6)
  x0 += ks2; x1 += k0 + 5u;
  *o0 = x0; *o1 = x1;
#undef TF_RND
#undef ROTL32
}

// keep-mask(e; key), bit-exact vs jax uniform+floor
__device__ __forceinline__ float drop_mask(uint32_t e, uint32_t k0, uint32_t k1) {
  uint32_t o0, o1;
  tf2x32(k0, k1, 0u, e, &o0, &o1);
  uint32_t bits = o0 ^ o1;
  float u = __uint_as_float((bits >> 9) | 0x3F800000u) - 1.0f;
  return floorf(u + 0.9f);
}

// bf16 helpers: RNE pack, exact shl unpack
__device__ __forceinline__ uint32_t f2bf(float f) {
  uint32_t u = __float_as_uint(f);
  return (u + 0x7fffu + ((u >> 16) & 1u)) >> 16;
}
__device__ __forceinline__ float bflo(uint32_t u) { return __uint_as_float(u << 16); }
__device__ __forceinline__ float bfhi(uint32_t u) { return __uint_as_float(u & 0xffff0000u); }

// ---------------------------------------------------------------------------
// CSR build (R5 structure): histogram -> hierarchical scan -> fused scatter.
// Per-ROW cursors (~13 edges/cursor, low contention; R6 lesson: bucket
// cursors serialize). Record is 8 B {col, bf16(v_l0) | bf16(v_l1)<<16}:
// 16 MB adj region fits aggregate L2 -> sibling records coalesce into full
// lines before writeback (R7: 16 B records = 126 MB partial-line writeback).
// ---------------------------------------------------------------------------
__global__ void hist_kernel(const int* __restrict__ rows, int* __restrict__ cnt, int nE) {
  int e = blockIdx.x * blockDim.x + threadIdx.x;
  if (e < nE) atomicAdd(&cnt[rows[e]], 1);
}

__global__ void scan1_kernel(const int* __restrict__ cnt, int* __restrict__ rp,
                             int* __restrict__ bsum, int n) {
  __shared__ int s[256];
  int t = threadIdx.x;
  int base = blockIdx.x * 1024 + t * 4;
  int c0 = (base + 0 < n) ? cnt[base + 0] : 0;
  int c1 = (base + 1 < n) ? cnt[base + 1] : 0;
  int c2 = (base + 2 < n) ? cnt[base + 2] : 0;
  int c3 = (base + 3 < n) ? cnt[base + 3] : 0;
  int tsum = c0 + c1 + c2 + c3;
  s[t] = tsum;
  __syncthreads();
  for (int off = 1; off < 256; off <<= 1) {
    int v = (t >= off) ? s[t - off] : 0;
    __syncthreads();
    s[t] += v;
    __syncthreads();
  }
  int excl = s[t] - tsum;
  if (base + 0 < n) rp[base + 0] = excl;
  if (base + 1 < n) rp[base + 1] = excl + c0;
  if (base + 2 < n) rp[base + 2] = excl + c0 + c1;
  if (base + 3 < n) rp[base + 3] = excl + c0 + c1 + c2;
  if (t == 255) bsum[blockIdx.x] = s[255];
}

__global__ void scan2_kernel(int* __restrict__ bsum, int B) {
  __shared__ int s[256];
  int t = threadIdx.x;
  int v = (t < B) ? bsum[t] : 0;
  s[t] = v;
  __syncthreads();
  for (int off = 1; off < 256; off <<= 1) {
    int x = (t >= off) ? s[t - off] : 0;
    __syncthreads();
    s[t] += x;
    __syncthreads();
  }
  if (t < B) bsum[t] = s[t] - v;
}

__global__ void scan3_kernel(int* __restrict__ rp, const int* __restrict__ bsum,
                             int* __restrict__ cursor, int n, int nE) {
  int i = blockIdx.x * blockDim.x + threadIdx.x;
  if (i < n) {
    int v = rp[i] + bsum[i >> 10];
    rp[i] = v;
    cursor[i] = v;
  }
  if (i == 0) rp[n] = nE;
}

// Fused scatter: per original edge e, compute BOTH layers' dropped values
// (threefry keyed on e -> bit-exact) packed as 2x bf16 in one 8 B record.
__global__ void scatter_fused_kernel(const int* __restrict__ rows, const int* __restrict__ cols,
                                     const float* __restrict__ vals,
                                     int* __restrict__ cursor, int2* __restrict__ rec, int nE,
                                     uint32_t ka0, uint32_t ka1, uint32_t kb0, uint32_t kb1) {
  int e = blockIdx.x * blockDim.x + threadIdx.x;
  if (e >= nE) return;
  const float SC = (float)(1.0 / 0.9);
  float v  = vals[e];
  float v0 = v * drop_mask((uint32_t)e, ka0, ka1) * SC;
  float v1 = v * drop_mask((uint32_t)e, kb0, kb1) * SC;
  uint32_t pk = f2bf(v0) | (f2bf(v1) << 16);   // dropped -> exact 0 bits
  int pos = atomicAdd(&cursor[rows[e]], 1);
  rec[pos] = make_int2(cols[e], (int)pk);
}

// ---------------------------------------------------------------------------
// Gather SpMM core, eighth-wave bf16 (R8): row = 64 bf16 = 8 lanes x uint4.
// Wave = 8 sub-groups of 8 lanes; group `sub` handles edge j+sub -> 8 edges
// per load instruction. WAVE-UNIFORM trip counts (R3 lesson): loop bounds
// depend only on uniform cnt; shfl idx j+sub <= 63 always; OOB/dropped edges
// have v = exact 0 (guard skips their load; guard is sub-group-uniform).
// Cross-subgroup reduce via shfl_xor(8/16/32). VS picks the layer value.
// ---------------------------------------------------------------------------
template <int VS>
__device__ __forceinline__ void gather_row8(int s0, int s1, const int2* __restrict__ rec,
                                            const ushort* __restrict__ srcA,
                                            const ushort* __restrict__ srcB,
                                            int split, int lane, int sub, int fl,
                                            float4& A0, float4& A1) {
  float4 a0 = make_float4(0.f, 0.f, 0.f, 0.f);
  float4 a1 = make_float4(0.f, 0.f, 0.f, 0.f);
  for (int base = s0; base < s1; base += 64) {
    int i = base + lane;
    int2 m = make_int2(0, 0);            // pad: col 0, v 0 (exact +0)
    if (i < s1) m = rec[i];
    int cnt = s1 - base;
    if (cnt > 64) cnt = 64;
    int j = 0;
    for (; j + 16 <= cnt; j += 16) {     // 2 independent edges per sub-group
      int      cA = __shfl(m.x, j + sub);
      uint32_t wA = (uint32_t)__shfl(m.y, j + sub);
      int      cB = __shfl(m.x, j + 8 + sub);
      uint32_t wB = (uint32_t)__shfl(m.y, j + 8 + sub);
      float vA = VS ? bfhi(wA) : bflo(wA);
      float vB = VS ? bfhi(wB) : bflo(wB);
      if (vA != 0.0f) {
        const ushort* p = (cA < split) ? srcA + (size_t)cA * DD : srcB + (size_t)(cA - split) * DD;
        uint4 q = ((const uint4*)p)[fl];
        a0.x += vA * bflo(q.x); a0.y += vA * bfhi(q.x);
        a0.z += vA * bflo(q.y); a0.w += vA * bfhi(q.y);
        a1.x += vA * bflo(q.z); a1.y += vA * bfhi(q.z);
        a1.z += vA * bflo(q.w); a1.w += vA * bfhi(q.w);
      }
      if (vB != 0.0f) {
        const ushort* p = (cB < split) ? srcA + (size_t)cB * DD : srcB + (size_t)(cB - split) * DD;
        uint4 q = ((const uint4*)p)[fl];
        a0.x += vB * bflo(q.x); a0.y += vB * bfhi(q.x);
        a0.z += vB * bflo(q.y); a0.w += vB * bfhi(q.y);
        a1.x += vB * bflo(q.z); a1.y += vB * bfhi(q.z);
        a1.z += vB * bflo(q.w); a1.w += vB * bfhi(q.w);
      }
    }
    for (; j < cnt; j += 8) {
      int      c = __shfl(m.x, j + sub);
      uint32_t w = (uint32_t)__shfl(m.y, j + sub);
      float v = VS ? bfhi(w) : bflo(w);
      if (v != 0.0f) {
        const ushort* p = (c < split) ? srcA + (size_t)c * DD : srcB + (size_t)(c - split) * DD;
        uint4 q = ((const uint4*)p)[fl];
        a0.x += v * bflo(q.x); a0.y += v * bfhi(q.x);
        a0.z += v * bflo(q.y); a0.w += v * bfhi(q.y);
        a1.x += v * bflo(q.z); a1.y += v * bfhi(q.z);
        a1.z += v * bflo(q.w); a1.w += v * bfhi(q.w);
      }
    }
  }
#define RED(c) { c += __shfl_xor(c, 8); c += __shfl_xor(c, 16); c += __shfl_xor(c, 32); }
  RED(a0.x) RED(a0.y) RED(a0.z) RED(a0.w)
  RED(a1.x) RED(a1.y) RED(a1.z) RED(a1.w)
#undef RED
  A0 = a0; A1 = a1;
}

__device__ __forceinline__ float4 lk4(float4 x) {
  x.x = x.x >= 0.0f ? x.x : 0.5f * x.x;
  x.y = x.y >= 0.0f ? x.y : 0.5f * x.y;
  x.z = x.z >= 0.0f ? x.z : 0.5f * x.z;
  x.w = x.w >= 0.0f ? x.w : 0.5f * x.w;
  return x;
}

__device__ __forceinline__ uint4 pack8(float4 a, float4 b) {
  uint4 p;
  p.x = f2bf(a.x) | (f2bf(a.y) << 16);
  p.y = f2bf(a.z) | (f2bf(a.w) << 16);
  p.z = f2bf(b.x) | (f2bf(b.y) << 16);
  p.w = f2bf(b.z) | (f2bf(b.w) << 16);
  return p;
}

// Tag-node rows only (rr in [0,TAG_N)): out(bf16) = leaky(tag-spmm row ITEM_N+rr)
__global__ void gather_tagrows_kernel(const int* __restrict__ rp, const int2* __restrict__ rec,
                                      const ushort* __restrict__ srcA, const ushort* __restrict__ srcB,
                                      ushort* __restrict__ out) {
  int rr = (blockIdx.x * blockDim.x + threadIdx.x) >> 6;
  if (rr >= TAG_N) return;
  int lane = threadIdx.x & 63, sub = lane >> 3, fl = lane & 7;
  int r = rr + ITEM_N;
  float4 a0, a1;
  gather_row8<0>(rp[r], rp[r + 1], rec, srcA, srcB, ITEM_N, lane, sub, fl, a0, a1);
  if (sub == 0)
    ((uint4*)(out + (size_t)rr * DD))[fl] = pack8(lk4(a0), lk4(a1));
}

// Mega gather over NN rows; tag gather for item rows fused inline.
// o = leaky(adj) + (r<USER ? leaky(soc) : leaky(tag_row))
// FINAL=false (layer 0): latOut(bf16) = o
// FINAL=true  (layer 1): acc(f32) += f32(lat[row]) + o   (lat = lat1 bf16)
template <int VS, bool FINAL>
__global__ void gather_mega_kernel(
    const int* __restrict__ arp, const int2* __restrict__ arec,
    const int* __restrict__ srp, const int2* __restrict__ srec,
    const int* __restrict__ trp, const int2* __restrict__ trec,
    const ushort* __restrict__ lat,   // NN x 64 bf16: src for adj & soc (& tag items)
    const ushort* __restrict__ tagB,  // tag-node src rows (tEmbf or tg1bf)
    ushort* __restrict__ latOut, float* __restrict__ acc) {
  int r = (blockIdx.x * blockDim.x + threadIdx.x) >> 6;
  if (r >= NN) return;
  int lane = threadIdx.x & 63, sub = lane >> 3, fl = lane & 7;
  float4 t0, t1, b0, b1;
  gather_row8<VS>(arp[r], arp[r + 1], arec, lat, lat, NN, lane, sub, fl, t0, t1);
  if (r < USER_N) {
    gather_row8<VS>(srp[r], srp[r + 1], srec, lat, lat, NN, lane, sub, fl, b0, b1);
  } else {
    int tr = r - USER_N;
    gather_row8<VS>(trp[tr], trp[tr + 1], trec,
                    lat + (size_t)USER_N * DD, tagB, ITEM_N, lane, sub, fl, b0, b1);
  }
  if (sub == 0) {
    t0 = lk4(t0); t1 = lk4(t1); b0 = lk4(b0); b1 = lk4(b1);
    float4 o0 = make_float4(t0.x + b0.x, t0.y + b0.y, t0.z + b0.z, t0.w + b0.w);
    float4 o1 = make_float4(t1.x + b1.x, t1.y + b1.y, t1.z + b1.z, t1.w + b1.w);
    if (FINAL) {
      uint4 l = ((const uint4*)(lat + (size_t)r * DD))[fl];
      float4* ap = (float4*)(acc + (size_t)r * DD);
      float4 v0 = ap[fl * 2], v1 = ap[fl * 2 + 1];
      v0.x += bflo(l.x) + o0.x; v0.y += bfhi(l.x) + o0.y;
      v0.z += bflo(l.y) + o0.z; v0.w += bfhi(l.y) + o0.w;
      v1.x += bflo(l.z) + o1.x; v1.y += bfhi(l.z) + o1.y;
      v1.z += bflo(l.w) + o1.z; v1.w += bfhi(l.w) + o1.w;
      ap[fl * 2] = v0; ap[fl * 2 + 1] = v1;
    } else {
      ((uint4*)(latOut + (size_t)r * DD))[fl] = pack8(o0, o1);
    }
  }
}

// acc(f32) = lat0 = concat(u, i); lat0bf = bf16(lat0); tEmbf = bf16(tEmbeds)
__global__ void init_kernel(const float4* __restrict__ u, const float4* __restrict__ it,
                            const float4* __restrict__ tE,
                            float4* __restrict__ acc, ushort4* __restrict__ lat0bf,
                            ushort4* __restrict__ tEmbf) {
  int idx = blockIdx.x * blockDim.x + threadIdx.x;  // NN*16 + TAG_N*16 float4s
  const int uN = USER_N * 16, nN = NN * 16;
  if (idx < nN) {
    float4 v = (idx < uN) ? u[idx] : it[idx - uN];
    acc[idx] = v;
    ushort4 h;
    h.x = (ushort)f2bf(v.x); h.y = (ushort)f2bf(v.y);
    h.z = (ushort)f2bf(v.z); h.w = (ushort)f2bf(v.w);
    lat0bf[idx] = h;
  } else if (idx < nN + TAG_N * 16) {
    int j = idx - nN;
    float4 v = tE[j];
    ushort4 h;
    h.x = (ushort)f2bf(v.x); h.y = (ushort)f2bf(v.y);
    h.z = (ushort)f2bf(v.z); h.w = (ushort)f2bf(v.w);
    tEmbf[j] = h;
  }
}

extern "C" void kernel_launch(void* const* d_in, const int* in_sizes, int n_in,
                              void* d_out, int out_size, void* d_ws, size_t ws_size,
                              hipStream_t stream) {
  const float* uE    = (const float*)d_in[0];
  const float* iE    = (const float*)d_in[1];
  const float* tEm   = (const float*)d_in[2];
  const int*   adj_r = (const int*)d_in[3];
  const int*   adj_c = (const int*)d_in[4];
  const float* adj_v = (const float*)d_in[5];
  const int*   tag_r = (const int*)d_in[6];
  const int*   tag_c = (const int*)d_in[7];
  const float* tag_v = (const float*)d_in[8];
  const int*   soc_r = (const int*)d_in[9];
  const int*   soc_c = (const int*)d_in[10];
  const float* soc_v = (const float*)d_in[11];
  const int nAdj = in_sizes[5], nTag = in_sizes[8], nSoc = in_sizes[11];

  float* acc = (float*)d_out;

  // Workspace (~78 MB). All bf16 blocks are 16B-aligned (sizes divisible by 16).
  ushort* lat0bf = (ushort*)d_ws;                  // NN*DD bf16
  ushort* lat1bf = lat0bf + (size_t)NN * DD;       // NN*DD
  ushort* tg1bf  = lat1bf + (size_t)NN * DD;       // TAG_N*DD
  ushort* tEmbf  = tg1bf  + (size_t)TAG_N * DD;    // TAG_N*DD
  int2* a_rec = (int2*)(tEmbf + (size_t)TAG_N * DD);  // nAdj {col, bf16v0|bf16v1}
  int2* t_rec = a_rec + nAdj;                      // nTag
  int2* s_rec = t_rec + nTag;                      // nSoc
  int* ip    = (int*)(s_rec + nSoc);
  int* a_rp  = ip;  ip += NN + 1;
  int* a_cur = ip;  ip += NN;
  int* t_rp  = ip;  ip += MM + 1;
  int* t_cur = ip;  ip += MM;
  int* s_rp  = ip;  ip += USER_N + 1;
  int* s_cur = ip;  ip += USER_N;
  int* bsum  = ip;  ip += 256;

  // fold_in(key(42), j) for j=0..5 (host-side, deterministic)
  uint32_t kk[6][2];
  for (uint32_t j = 0; j < 6; ++j) tf2x32(0u, 42u, 0u, j, &kk[j][0], &kk[j][1]);

  const int thr = 256;
#define CDIV(a, b) (((a) + (b) - 1) / (b))

  // ---- CSR build (once per call; records carry both layers' values) ----
  struct G { const int* rows; const int* cols; const float* vals; int n; int nE;
             int* rp; int* cur; int2* rec; int k0; int k1; };
  G gs[3] = {
      {adj_r, adj_c, adj_v, NN,     nAdj, a_rp, a_cur, a_rec, 0, 3},
      {tag_r, tag_c, tag_v, MM,     nTag, t_rp, t_cur, t_rec, 1, 4},
      {soc_r, soc_c, soc_v, USER_N, nSoc, s_rp, s_cur, s_rec, 2, 5},
  };
  for (int g = 0; g < 3; ++g) {
    hipMemsetAsync(gs[g].cur, 0, (size_t)gs[g].n * sizeof(int), stream);
    hist_kernel<<<CDIV(gs[g].nE, thr), thr, 0, stream>>>(gs[g].rows, gs[g].cur, gs[g].nE);
    int B = CDIV(gs[g].n, 1024);
    scan1_kernel<<<B, 256, 0, stream>>>(gs[g].cur, gs[g].rp, bsum, gs[g].n);
    scan2_kernel<<<1, 256, 0, stream>>>(bsum, B);
    scan3_kernel<<<CDIV(gs[g].n, thr), thr, 0, stream>>>(gs[g].rp, bsum, gs[g].cur, gs[g].n, gs[g].nE);
    scatter_fused_kernel<<<CDIV(gs[g].nE, thr), thr, 0, stream>>>(
        gs[g].rows, gs[g].cols, gs[g].vals, gs[g].cur, gs[g].rec, gs[g].nE,
        kk[gs[g].k0][0], kk[gs[g].k0][1], kk[gs[g].k1][0], kk[gs[g].k1][1]);
  }

  // ---- init: acc = lat0 (f32); lat0bf, tEmbf (bf16 gather sources) ----
  init_kernel<<<CDIV((NN + TAG_N) * 16, thr), thr, 0, stream>>>(
      (const float4*)uE, (const float4*)iE, (const float4*)tEm,
      (float4*)acc, (ushort4*)lat0bf, (ushort4*)tEmbf);

  // ---- layer 0 ----
  // tg1 = leaky(tag-spmm) for tag-node rows (layer-1 tag sources)
  gather_tagrows_kernel<<<CDIV(TAG_N * 64, thr), thr, 0, stream>>>(
      t_rp, t_rec, lat0bf + (size_t)USER_N * DD, tEmbf, tg1bf);

  // lat1 = combine(leaky(adj), leaky(soc) | leaky(tag item rows)); acc untouched
  gather_mega_kernel<0, false><<<CDIV(NN * 64, thr), thr, 0, stream>>>(
      a_rp, a_rec, s_rp, s_rec, t_rp, t_rec, lat0bf, tEmbf, lat1bf, nullptr);

  // ---- layer 1 ----
  // acc += lat1 + combine(leaky(adj), leaky(soc) | leaky(tag item rows))
  gather_mega_kernel<1, true><<<CDIV(NN * 64, thr), thr, 0, stream>>>(
      a_rp, a_rec, s_rp, s_rec, t_rp, t_rec, lat1bf, tg1bf, nullptr, acc);
#undef CDIV
}